// Round 7
// baseline (130.816 us; speedup 1.0000x reference)
//
#include <hip/hip_runtime.h>
#include <hip/hip_bf16.h>
#include <stdint.h>

// ---------------------------------------------------------------------------
// SupervisedContrastiveLoss, B=4096, D=1024, C=32, T=0.1, eps=1e-8
// out = (1/B) * [ sum_i (log(denom_i)*W_i - posS_i) - pw*INV_T*||G||_F^2 ]
// R7: LDS-FREE register-fragment GEMM. stage1 packs rn-fp8(x16) into MFMA
//     fragment order: rnP[slab][kt][lane]*8B, slab=row/16, kt=k/32,
//     lane=(g2<<4)|m holds A[m][kt*32+g2*8..+8]. Gemm loads frags as ONE
//     coalesced 512-B dwordx2 per (slab,kt) — no LDS, no barriers, no GLD-LDS.
// ---------------------------------------------------------------------------

typedef float f32x4 __attribute__((ext_vector_type(4)));
typedef float f32x2 __attribute__((ext_vector_type(2)));
typedef long i64;

#define INV_T 10.0f
#define Z_SCALE (INV_T / 256.0f)   // both fp8 operands carry x16

// workspace layout (bytes)
#define OFF_RNF8  0                         // packed: 256 slabs * 16384 = 4194304
#define OFF_DENOM 4194304                   // 4096*4
#define OFF_POSS  (OFF_DENOM + 16384)
#define OFF_G     (OFF_POSS + 16384)        // 1024*32*4 = 131072
#define OFF_OACC  (OFF_G + 131072)          // double
#define OFF_DONE  (OFF_OACC + 16)           // int
#define ZERO_SPAN 167936                    // 41*4096 >= 163904 (zeroed region)
#define OFF_CSP   (OFF_DENOM + ZERO_SPAN)   // 32*32*4 colsum partials
#define OFF_CCP   (OFF_CSP + 4096)          // 32*32*4 histogram partials

// ---------------- D1: normalize+pack (256) | prep (32) | zero (41) ----------
__global__ __launch_bounds__(256) void scl_stage1(const float* __restrict__ rep,
                                                  const float* __restrict__ sl,
                                                  const int* __restrict__ labels,
                                                  uint8_t* __restrict__ rnP,
                                                  float* __restrict__ cs_part,
                                                  int* __restrict__ cc_part,
                                                  char* __restrict__ zbase) {
    int b = blockIdx.x;
    int t = threadIdx.x;
    if (b < 256) {
        // slab b: rows b*16 .. +15 -> packed 16 KB block
        __shared__ uint32_t Ls32[4096];  // 16 KB packed staging
        int rl = t >> 4, i = t & 15;
        int row = b * 16 + rl;
        const float4* src = (const float4*)(rep + (size_t)row * 1024);
        // pass 1: sumsq (cols i*4 + j*64, coalesced within 16-lane row group)
        float s = 0.f;
#pragma unroll
        for (int j = 0; j < 16; ++j) {
            float4 v = src[i + j * 16];
            s += v.x * v.x + v.y * v.y + v.z * v.z + v.w * v.w;
        }
#pragma unroll
        for (int m = 1; m < 16; m <<= 1) s += __shfl_xor(s, m, 64);
        float nf = 16.0f / fmaxf(sqrtf(s), 1e-8f);  // x16 into fp8 normal range
        // pass 2: convert + scatter into packed LDS
        // col c = i*4 + j*64 -> kt=j*2+(i>>3), g2=(i>>1)&3, byte=(i&1)*4, m=rl
        int g2 = (i >> 1) & 3;
        int dw = ((g2 * 16 + rl) * 8 + (i & 1) * 4) >> 2;  // dword within 512-B blk
#pragma unroll
        for (int j = 0; j < 16; ++j) {
            float4 v = src[i + j * 16];
            int pk = 0;
            pk = __builtin_amdgcn_cvt_pk_fp8_f32(v.x * nf, v.y * nf, pk, false);
            pk = __builtin_amdgcn_cvt_pk_fp8_f32(v.z * nf, v.w * nf, pk, true);
            int kt = j * 2 + (i >> 3);
            Ls32[kt * 128 + dw] = (uint32_t)pk;
        }
        __syncthreads();
        // linear copy LDS -> global packed (coalesced 16 KB)
        uint4* dst = (uint4*)(rnP + (size_t)b * 16384);
        const uint4* srcl = (const uint4*)Ls32;
#pragma unroll
        for (int q = 0; q < 4; ++q) dst[t * 4 + q] = srcl[t * 4 + q];
    } else if (b < 288) {
        // prep partials: colsum of soft_labels + class histogram (128 rows/slab)
        __shared__ float part[8][32];
        __shared__ int bins[32];
        int bb = b - 256;
        if (t < 32) bins[t] = 0;
        __syncthreads();
        if (t < 128) atomicAdd(&bins[labels[bb * 128 + t]], 1);
        int c = t & 31, rg = t >> 5;
        float s = 0.f;
#pragma unroll 4
        for (int k = 0; k < 16; ++k) {
            int i = bb * 128 + rg * 16 + k;
            s += sl[i * 32 + c];
        }
        part[rg][c] = s;
        __syncthreads();
        if (t < 32) {
            float tot = 0.f;
#pragma unroll
            for (int g = 0; g < 8; ++g) tot += part[g][t];
            cs_part[bb * 32 + t] = tot;
            cc_part[bb * 32 + t] = bins[t];
        }
    } else {
        // zero blocks: denom/posS/G/oacc/done
        int zb = b - 288;
        *(uint4*)(zbase + (size_t)zb * 4096 + t * 16) = (uint4){0, 0, 0, 0};
    }
}

// ---------------- D2: LDS-free gemm (1 wave/tile) + G units -----------------
// blocks [0,2080): upper-tri 64x64 tiles. blocks [2080,3104): G units.
__global__ __launch_bounds__(64) void scl_main(const uint8_t* __restrict__ rnP,
                                               const float* __restrict__ sl,
                                               const int* __restrict__ labels,
                                               float* __restrict__ denom,
                                               float* __restrict__ posS,
                                               float* __restrict__ G) {
    int lane = threadIdx.x;

    if (blockIdx.x >= 2080) {
        // ---- G unit: 32 d x 128 rows;  d0 = dblk*32 + dq*16 ----
        int u = blockIdx.x - 2080;
        int dblk = u & 31, ks = u >> 5;
        int c = lane & 31, dq = lane >> 5;  // dq in {0,1}
        f32x2 acc2[8];
#pragma unroll
        for (int j = 0; j < 8; ++j) acc2[j] = (f32x2){0.f, 0.f};
        int i0 = ks * 128;
#pragma unroll 2
        for (int k = 0; k < 128; ++k) {
            int i = i0 + k;
            // packed frag addr: slab=i>>4, kt=dblk, g2=dq*2(+1), m=i&15
            const uint8_t* fb = rnP + (size_t)(i >> 4) * 16384 + dblk * 512 +
                                (dq * 32 + (i & 15)) * 8;
            uint2 r01 = *(const uint2*)fb;          // d0..d7
            uint2 r23 = *(const uint2*)(fb + 128);  // d8..d15
            float sv = sl[i * 32 + c];
            f32x2 sv2 = {sv, sv};
            acc2[0] += __builtin_amdgcn_cvt_pk_f32_fp8((int)r01.x, false) * sv2;
            acc2[1] += __builtin_amdgcn_cvt_pk_f32_fp8((int)r01.x, true) * sv2;
            acc2[2] += __builtin_amdgcn_cvt_pk_f32_fp8((int)r01.y, false) * sv2;
            acc2[3] += __builtin_amdgcn_cvt_pk_f32_fp8((int)r01.y, true) * sv2;
            acc2[4] += __builtin_amdgcn_cvt_pk_f32_fp8((int)r23.x, false) * sv2;
            acc2[5] += __builtin_amdgcn_cvt_pk_f32_fp8((int)r23.x, true) * sv2;
            acc2[6] += __builtin_amdgcn_cvt_pk_f32_fp8((int)r23.y, false) * sv2;
            acc2[7] += __builtin_amdgcn_cvt_pk_f32_fp8((int)r23.y, true) * sv2;
        }
        int d0 = dblk * 32 + dq * 16;
#pragma unroll
        for (int j = 0; j < 8; ++j) {
            atomicAdd(&G[(d0 + 2 * j) * 32 + c], acc2[j][0] * 0.0625f);
            atomicAdd(&G[(d0 + 2 * j + 1) * 32 + c], acc2[j][1] * 0.0625f);
        }
        return;
    }

    // ---- gemm tile: one wave, 64x64, register fragments only ----
    int L = blockIdx.x;
    int bi = 0, rem = L;
    while (rem >= 64 - bi) { rem -= 64 - bi; ++bi; }
    int bj = bi + rem;
    int rowA0 = bi * 64, colB0 = bj * 64;

    int m_ = lane & 15, g = lane >> 4;

    const uint8_t* pa[4];
    const uint8_t* pb[4];
#pragma unroll
    for (int ti = 0; ti < 4; ++ti) {
        pa[ti] = rnP + (size_t)((rowA0 >> 4) + ti) * 16384 + lane * 8;
        pb[ti] = rnP + (size_t)((colB0 >> 4) + ti) * 16384 + lane * 8;
    }

    f32x4 acc[4][4];
#pragma unroll
    for (int a = 0; a < 4; ++a)
#pragma unroll
        for (int b = 0; b < 4; ++b) acc[a][b] = (f32x4){0.f, 0.f, 0.f, 0.f};

#define LOADK(KT, AA, BB)                                                      \
    {                                                                          \
        _Pragma("unroll") for (int ti = 0; ti < 4; ++ti) {                     \
            AA[ti] = *(const i64*)(pa[ti] + (KT) * 512);                       \
            BB[ti] = *(const i64*)(pb[ti] + (KT) * 512);                       \
        }                                                                      \
    }
#define MFMAB(AA, BB)                                                          \
    {                                                                          \
        _Pragma("unroll") for (int ti = 0; ti < 4; ++ti)                       \
            _Pragma("unroll") for (int tj = 0; tj < 4; ++tj)                   \
                acc[ti][tj] = __builtin_amdgcn_mfma_f32_16x16x32_fp8_fp8(      \
                    AA[ti], BB[tj], acc[ti][tj], 0, 0, 0);                     \
    }

    i64 a0[4], b0[4], a1[4], b1[4];
    LOADK(0, a0, b0);
    LOADK(1, a1, b1);
#pragma unroll
    for (int kt = 0; kt < 32; kt += 2) {
        MFMAB(a0, b0);
        if (kt + 2 < 32) LOADK(kt + 2, a0, b0);
        MFMAB(a1, b1);
        if (kt + 3 < 32) LOADK(kt + 3, a1, b1);
    }
#undef LOADK
#undef MFMAB

    // epilogue: C layout col=lane&15, row=(lane>>4)*4+reg
    bool isDiag = (bi == bj);
    int cl = m_;
    float colE[4] = {0.f, 0.f, 0.f, 0.f}, colP[4] = {0.f, 0.f, 0.f, 0.f};
    int lcj[4];
#pragma unroll
    for (int tj = 0; tj < 4; ++tj) lcj[tj] = labels[colB0 + tj * 16 + cl];
#pragma unroll
    for (int ti = 0; ti < 4; ++ti) {
        int rowLoc = ti * 16 + g * 4;
        float rE[4] = {0.f, 0.f, 0.f, 0.f}, rP[4] = {0.f, 0.f, 0.f, 0.f};
        int lr[4];
#pragma unroll
        for (int r = 0; r < 4; ++r) lr[r] = labels[rowA0 + rowLoc + r];
#pragma unroll
        for (int tj = 0; tj < 4; ++tj) {
            int gCol = colB0 + tj * 16 + cl;
            int lc = lcj[tj];
            f32x4 a = acc[ti][tj];
#pragma unroll
            for (int r = 0; r < 4; ++r) {
                int gRow = rowA0 + rowLoc + r;
                float z = Z_SCALE * a[r];
                float e = __expf(z);
                bool offd = (gRow != gCol);
                if (!offd) e = 0.f;
                rE[r] += e;
                colE[tj] += e;
                if (offd && (lr[r] == lc)) { rP[r] += z; colP[tj] += z; }
            }
        }
#pragma unroll
        for (int r = 0; r < 4; ++r) {
            float v = rE[r], p = rP[r];
#pragma unroll
            for (int msk = 1; msk < 16; msk <<= 1) {
                v += __shfl_xor(v, msk, 64);
                p += __shfl_xor(p, msk, 64);
            }
            if (cl == 0) {
                int gRow = rowA0 + rowLoc + r;
                atomicAdd(&denom[gRow], v);
                atomicAdd(&posS[gRow], p);
            }
        }
    }
    if (!isDiag) {
#pragma unroll
        for (int tj = 0; tj < 4; ++tj) {
            float v = colE[tj], p = colP[tj];
            v += __shfl_xor(v, 16, 64); p += __shfl_xor(p, 16, 64);
            v += __shfl_xor(v, 32, 64); p += __shfl_xor(p, 32, 64);
            if (g == 0) {
                int gCol = colB0 + tj * 16 + cl;
                atomicAdd(&denom[gCol], v);
                atomicAdd(&posS[gCol], p);
            }
        }
    }
}

// ---------------- D3: finalize (8 row-blocks + 1 G-block), done-counter -----
__global__ __launch_bounds__(256) void scl_finalize(const float* __restrict__ denom,
                                                    const float* __restrict__ posS,
                                                    const float* __restrict__ sl,
                                                    const int* __restrict__ labels,
                                                    const float* __restrict__ cs_part,
                                                    const int* __restrict__ cc_part,
                                                    const float* __restrict__ G,
                                                    const int* __restrict__ pwp,
                                                    double* __restrict__ oacc,
                                                    int* __restrict__ done,
                                                    float* __restrict__ out) {
    int t = threadIdx.x;
    int bits = *pwp;
    float pw = (bits >= -(1 << 22) && bits <= (1 << 22)) ? (float)bits
                                                         : __int_as_float(bits);
    __shared__ double wsum[4];
    double contrib = 0.0;

    if (blockIdx.x < 8) {
        __shared__ __align__(16) float css[32];
        __shared__ int ccs[32];
        if (t < 32) {
            float s = 0.f; int n = 0;
#pragma unroll
            for (int b = 0; b < 32; ++b) {
                s += cs_part[b * 32 + t];
                n += cc_part[b * 32 + t];
            }
            css[t] = s; ccs[t] = n;
        }
        __syncthreads();
        const f32x4* sl4 = (const f32x4*)sl;
        const f32x4* cs4 = (const f32x4*)css;
        double td = 0.0;
#pragma unroll
        for (int h = 0; h < 2; ++h) {
            int i = blockIdx.x * 512 + h * 256 + t;
            float dW = 0.f;
#pragma unroll
            for (int q = 0; q < 8; ++q) {
                f32x4 s = sl4[i * 8 + q];
                f32x4 c = cs4[q];
                dW += s[0] * c[0] + s[1] * c[1] + s[2] * c[2] + s[3] * c[3];
            }
            float Wv = (float)(ccs[labels[i]] - 1) + pw * dW;
            td += (double)(__logf(denom[i]) * Wv - posS[i]);
        }
#pragma unroll
        for (int m = 1; m < 64; m <<= 1) td += __shfl_xor(td, m, 64);
        if ((t & 63) == 0) wsum[t >> 6] = td;
        __syncthreads();
        contrib = wsum[0] + wsum[1] + wsum[2] + wsum[3];
    } else {
        const f32x4* G4 = (const f32x4*)G;
        float gs = 0.f;
#pragma unroll
        for (int q = 0; q < 32; ++q) {
            f32x4 v = G4[q * 256 + t];
            gs += v[0] * v[0] + v[1] * v[1] + v[2] * v[2] + v[3] * v[3];
        }
        double gd = (double)gs;
#pragma unroll
        for (int m = 1; m < 64; m <<= 1) gd += __shfl_xor(gd, m, 64);
        if ((t & 63) == 0) wsum[t >> 6] = gd;
        __syncthreads();
        contrib = -(double)(pw * INV_T) * (wsum[0] + wsum[1] + wsum[2] + wsum[3]);
    }

    if (t == 0) {
        atomicAdd(oacc, contrib);
        __threadfence();
        int old = atomicAdd(done, 1);
        if (old == 8) {  // last of 9 blocks
            double tot = atomicAdd(oacc, 0.0);  // coherent read
            out[0] = (float)(tot * (1.0 / 4096.0));
        }
    }
}

// ---------------------------------------------------------------------------
extern "C" void kernel_launch(void* const* d_in, const int* in_sizes, int n_in,
                              void* d_out, int out_size, void* d_ws, size_t ws_size,
                              hipStream_t stream) {
    const float* rep = (const float*)d_in[0];
    const float* sl = (const float*)d_in[1];
    const int* labels = (const int*)d_in[2];
    const int* pwp = (const int*)d_in[3];

    char* ws = (char*)d_ws;
    uint8_t* rnP = (uint8_t*)(ws + OFF_RNF8);
    float* denom = (float*)(ws + OFF_DENOM);
    float* posS = (float*)(ws + OFF_POSS);
    float* G = (float*)(ws + OFF_G);
    double* oacc = (double*)(ws + OFF_OACC);
    int* done = (int*)(ws + OFF_DONE);
    float* cs_part = (float*)(ws + OFF_CSP);
    int* cc_part = (int*)(ws + OFF_CCP);

    scl_stage1<<<329, 256, 0, stream>>>(rep, sl, labels, rnP, cs_part, cc_part,
                                        ws + OFF_DENOM);
    scl_main<<<3104, 64, 0, stream>>>(rnP, sl, labels, denom, posS, G);
    scl_finalize<<<9, 256, 0, stream>>>(denom, posS, sl, labels, cs_part, cc_part,
                                        G, pwp, oacc, done, (float*)d_out);
}